// Round 1
// baseline (118.925 us; speedup 1.0000x reference)
//
#include <hip/hip_runtime.h>

// TuckERInteraction: scores[n'] = sum_i u[n',i] * v[n',i]
//   v[n',i] = sum_j W[n'>>8, i, j] * t_bn[n', j]        (stage A, grouped by k = n'>>8)
//   u[n',i] = sum_a h_bn[n',a] * r[(n'&255)*128+a, i]   (stage B, grouped by low = n'&255)
// Derived from the reference's scrambled reshape of einsum('ni,kij->knj').
// N = 32768, D = 128. U/V stored bf16 in d_ws (16 MB total).

typedef __attribute__((ext_vector_type(8))) short bf16x8;   // MFMA A/B fragment (8 bf16)
typedef __attribute__((ext_vector_type(4))) short s16x4;
typedef __attribute__((ext_vector_type(4))) float f32x4;

#define DPAD 136   // LDS row stride (elements): 272 B -> 4-bank rotation, <=2-way conflicts
#define BN_EPS 1e-5f

__device__ inline unsigned short f2bf(float f) {
  unsigned u = __builtin_bit_cast(unsigned, f);
  u += 0x7FFFu + ((u >> 16) & 1u);          // round-to-nearest-even
  return (unsigned short)(u >> 16);
}
__device__ inline float bf2f(unsigned short h) {
  unsigned u = ((unsigned)h) << 16;
  return __builtin_bit_cast(float, u);
}

// ---------------- Stage A: V[n', i] = sum_j W[k,i,j] * t_bn[n', j] ----------------
// grid 256: block = (k, half); 128 rows of n' = k*256 + half*128 + m
__global__ __launch_bounds__(256) void k_stageA(
    const float* __restrict__ t, const float* __restrict__ W,
    const float* __restrict__ gamma1, const float* __restrict__ beta1,
    const float* __restrict__ mean1, const float* __restrict__ var1,
    unsigned short* __restrict__ V) {
  __shared__ short Tl[128 * DPAD];  // Tl[m][j] = bf16(t_bn[rowbase+m, j])
  __shared__ short Wl[128 * DPAD];  // Wl[i][j] = bf16(W[k, i, j])
  const int tid = threadIdx.x;
  const int k = blockIdx.x >> 1;
  const int half = blockIdx.x & 1;
  const int rowbase = k * 256 + half * 128;

  // staging: c = column quad (4 floats), rr = row within 8-row step
  const int c = tid & 31;
  const int rr = tid >> 5;
  f32x4 g  = *(const f32x4*)(gamma1 + c * 4);
  f32x4 be = *(const f32x4*)(beta1  + c * 4);
  f32x4 mu = *(const f32x4*)(mean1  + c * 4);
  f32x4 va = *(const f32x4*)(var1   + c * 4);
  f32x4 sc, bi;
  for (int q = 0; q < 4; ++q) {
    sc[q] = g[q] * rsqrtf(va[q] + BN_EPS);
    bi[q] = be[q] - mu[q] * sc[q];
  }
  const float* tbase = t + (size_t)rowbase * 128;
  const float* wbase = W + (size_t)k * 16384;
  for (int it = 0; it < 16; ++it) {
    const int m = it * 8 + rr;
    f32x4 tv = *(const f32x4*)(tbase + m * 128 + c * 4);
    s16x4 tb;
    for (int q = 0; q < 4; ++q) tb[q] = (short)f2bf(tv[q] * sc[q] + bi[q]);
    *(s16x4*)(&Tl[m * DPAD + c * 4]) = tb;
    f32x4 wv = *(const f32x4*)(wbase + m * 128 + c * 4);
    s16x4 wb;
    for (int q = 0; q < 4; ++q) wb[q] = (short)f2bf(wv[q]);
    *(s16x4*)(&Wl[m * DPAD + c * 4]) = wb;
  }
  __syncthreads();

  // compute: wave w -> rows [w*32, w*32+32), full 128 cols; 2x8 tiles of 16x16
  const int wv_ = tid >> 6;
  const int lane = tid & 63;
  const int l16 = lane & 15;
  const int quad = lane >> 4;
  f32x4 acc[2][8];
  for (int mt = 0; mt < 2; ++mt)
    for (int nt = 0; nt < 8; ++nt) acc[mt][nt] = (f32x4){0.f, 0.f, 0.f, 0.f};

  for (int ks = 0; ks < 4; ++ks) {
    const int K0 = ks * 32 + quad * 8;
    bf16x8 a[2], b[8];
    for (int mt = 0; mt < 2; ++mt)
      a[mt] = *(const bf16x8*)(&Tl[(wv_ * 32 + mt * 16 + l16) * DPAD + K0]);
    for (int nt = 0; nt < 8; ++nt)
      b[nt] = *(const bf16x8*)(&Wl[(nt * 16 + l16) * DPAD + K0]);
    for (int mt = 0; mt < 2; ++mt)
      for (int nt = 0; nt < 8; ++nt)
        acc[mt][nt] = __builtin_amdgcn_mfma_f32_16x16x32_bf16(a[mt], b[nt], acc[mt][nt], 0, 0, 0);
  }

  for (int mt = 0; mt < 2; ++mt) {
    const int rbase2 = rowbase + wv_ * 32 + mt * 16 + quad * 4;
    for (int nt = 0; nt < 8; ++nt) {
      const int col = nt * 16 + l16;
      for (int rg = 0; rg < 4; ++rg)
        V[(size_t)(rbase2 + rg) * 128 + col] = f2bf(acc[mt][nt][rg]);
    }
  }
}

// ---------------- Stage B: U[n', i] = sum_a h_bn[n', a] * r[low*128+a, i] ----------------
// grid 256: block = low; rows n' = kk*256 + low, kk = 0..127
__global__ __launch_bounds__(256) void k_stageB(
    const float* __restrict__ h, const float* __restrict__ r,
    const float* __restrict__ gamma0, const float* __restrict__ beta0,
    const float* __restrict__ mean0, const float* __restrict__ var0,
    unsigned short* __restrict__ U) {
  __shared__ short Hl[128 * DPAD];  // Hl[kk][a] = bf16(h_bn[kk*256+low, a])
  __shared__ short Rl[128 * DPAD];  // Rl[i][a]  = bf16(r[low*128+a, i])   (transposed)
  const int tid = threadIdx.x;
  const int low = blockIdx.x;

  const int c = tid & 31;
  const int rr = tid >> 5;
  f32x4 g  = *(const f32x4*)(gamma0 + c * 4);
  f32x4 be = *(const f32x4*)(beta0  + c * 4);
  f32x4 mu = *(const f32x4*)(mean0  + c * 4);
  f32x4 va = *(const f32x4*)(var0   + c * 4);
  f32x4 sc, bi;
  for (int q = 0; q < 4; ++q) {
    sc[q] = g[q] * rsqrtf(va[q] + BN_EPS);
    bi[q] = be[q] - mu[q] * sc[q];
  }
  for (int it = 0; it < 16; ++it) {
    const int kk = it * 8 + rr;
    f32x4 hv = *(const f32x4*)(h + ((size_t)(kk * 256 + low)) * 128 + c * 4);
    s16x4 hb;
    for (int q = 0; q < 4; ++q) hb[q] = (short)f2bf(hv[q] * sc[q] + bi[q]);
    *(s16x4*)(&Hl[kk * DPAD + c * 4]) = hb;
  }
  // transpose-stage r: thread owns 4x4 block (rows a0..a0+3, cols 4c..4c+3)
  for (int it = 0; it < 4; ++it) {
    const int a0 = it * 32 + rr * 4;
    f32x4 rv[4];
    for (int v = 0; v < 4; ++v)
      rv[v] = *(const f32x4*)(r + ((size_t)(low * 128 + a0 + v)) * 128 + c * 4);
    for (int u = 0; u < 4; ++u) {
      s16x4 w;
      for (int v = 0; v < 4; ++v) w[v] = (short)f2bf(rv[v][u]);
      *(s16x4*)(&Rl[(c * 4 + u) * DPAD + a0]) = w;
    }
  }
  __syncthreads();

  const int wv_ = tid >> 6;
  const int lane = tid & 63;
  const int l16 = lane & 15;
  const int quad = lane >> 4;
  f32x4 acc[2][8];
  for (int mt = 0; mt < 2; ++mt)
    for (int nt = 0; nt < 8; ++nt) acc[mt][nt] = (f32x4){0.f, 0.f, 0.f, 0.f};

  for (int ks = 0; ks < 4; ++ks) {
    const int K0 = ks * 32 + quad * 8;
    bf16x8 a[2], b[8];
    for (int mt = 0; mt < 2; ++mt)
      a[mt] = *(const bf16x8*)(&Hl[(wv_ * 32 + mt * 16 + l16) * DPAD + K0]);
    for (int nt = 0; nt < 8; ++nt)
      b[nt] = *(const bf16x8*)(&Rl[(nt * 16 + l16) * DPAD + K0]);
    for (int mt = 0; mt < 2; ++mt)
      for (int nt = 0; nt < 8; ++nt)
        acc[mt][nt] = __builtin_amdgcn_mfma_f32_16x16x32_bf16(a[mt], b[nt], acc[mt][nt], 0, 0, 0);
  }

  for (int mt = 0; mt < 2; ++mt) {
    const int kkbase = wv_ * 32 + mt * 16 + quad * 4;
    for (int nt = 0; nt < 8; ++nt) {
      const int col = nt * 16 + l16;
      for (int rg = 0; rg < 4; ++rg)
        U[(size_t)((kkbase + rg) * 256 + low) * 128 + col] = f2bf(acc[mt][nt][rg]);
    }
  }
}

// ---------------- Stage C: scores[n'] = dot(U[n'], V[n']) ----------------
__global__ __launch_bounds__(256) void k_dot(
    const unsigned short* __restrict__ U, const unsigned short* __restrict__ V,
    float* __restrict__ out) {
  const int tid = threadIdx.x;
  const int row = blockIdx.x * 16 + (tid >> 4);
  const int l = tid & 15;
  const uint4 uv = *(const uint4*)(U + (size_t)row * 128 + l * 8);
  const uint4 vv = *(const uint4*)(V + (size_t)row * 128 + l * 8);
  const unsigned* up = (const unsigned*)&uv;
  const unsigned* vp = (const unsigned*)&vv;
  float s = 0.f;
  for (int q = 0; q < 4; ++q) {
    unsigned a = up[q], b = vp[q];
    s += bf2f((unsigned short)(a & 0xFFFFu)) * bf2f((unsigned short)(b & 0xFFFFu));
    s += bf2f((unsigned short)(a >> 16)) * bf2f((unsigned short)(b >> 16));
  }
  for (int m = 1; m < 16; m <<= 1) s += __shfl_xor(s, m, 16);
  if (l == 0) out[row] = s;
}

extern "C" void kernel_launch(void* const* d_in, const int* in_sizes, int n_in,
                              void* d_out, int out_size, void* d_ws, size_t ws_size,
                              hipStream_t stream) {
  const float* h      = (const float*)d_in[0];
  const float* r      = (const float*)d_in[1];
  const float* t      = (const float*)d_in[2];
  const float* W      = (const float*)d_in[3];
  const float* gamma0 = (const float*)d_in[4];
  const float* beta0  = (const float*)d_in[5];
  const float* mean0  = (const float*)d_in[6];
  const float* var0   = (const float*)d_in[7];
  const float* gamma1 = (const float*)d_in[8];
  const float* beta1  = (const float*)d_in[9];
  const float* mean1  = (const float*)d_in[10];
  const float* var1   = (const float*)d_in[11];
  float* out = (float*)d_out;

  unsigned short* V = (unsigned short*)d_ws;                 // 32768*128 bf16 = 8 MB
  unsigned short* U = V + (size_t)32768 * 128;               // 8 MB more (ws >= 16 MB)

  k_stageA<<<256, 256, 0, stream>>>(t, W, gamma1, beta1, mean1, var1, V);
  k_stageB<<<256, 256, 0, stream>>>(h, r, gamma0, beta0, mean0, var0, U);
  k_dot<<<2048, 256, 0, stream>>>(U, V, out);
}

// Round 3
// 116.836 us; speedup vs baseline: 1.0179x; 1.0179x over previous
//
#include <hip/hip_runtime.h>

// TuckERInteraction: scores[n'] = sum_i u[n',i] * v[n',i]
//   v[n',i] = sum_j W[n'>>8, i, j] * t_bn[n', j]        (stage A, grouped by k = n'>>8)
//   u[n',i] = sum_a h_bn[n',a] * r[(n'&255)*128+a, i]   (stage B, grouped by low = n'&255)
// N = 32768, D = 128. U/V stored bf16 in d_ws (16 MB total).
//
// R3: fix R2's grid-split bug (stage A is 256 blocks, not 512 — R2 read 8 MB
// past W's end -> GPU fault). Keeps R2's fusion + swapped-operand packed
// stores (lane's 4 acc regs = 4 consecutive feature cols -> uint2 stores).

typedef __attribute__((ext_vector_type(8))) short bf16x8;   // MFMA A/B fragment (8 bf16)
typedef __attribute__((ext_vector_type(4))) short s16x4;
typedef __attribute__((ext_vector_type(4))) float f32x4;

#define DPAD 136   // LDS row stride (elements)
#define BN_EPS 1e-5f

__device__ inline unsigned short f2bf(float f) {
  unsigned u = __builtin_bit_cast(unsigned, f);
  u += 0x7FFFu + ((u >> 16) & 1u);          // round-to-nearest-even
  return (unsigned short)(u >> 16);
}
__device__ inline float bf2f(unsigned short h) {
  unsigned u = ((unsigned)h) << 16;
  return __builtin_bit_cast(float, u);
}
__device__ inline unsigned pack2bf(float lo, float hi) {
  return (unsigned)f2bf(lo) | ((unsigned)f2bf(hi) << 16);
}

// ---------------- Fused stage A + stage B ----------------
// blocks [0,256): stage A, block = (k, half): V rows n' = k*256 + half*128 + m
// blocks [256,512): stage B, block = low:     U rows n' = kk*256 + low
__global__ __launch_bounds__(256) void k_uv(
    const float* __restrict__ h, const float* __restrict__ r,
    const float* __restrict__ t, const float* __restrict__ W,
    const float* __restrict__ gamma0, const float* __restrict__ beta0,
    const float* __restrict__ mean0, const float* __restrict__ var0,
    const float* __restrict__ gamma1, const float* __restrict__ beta1,
    const float* __restrict__ mean1, const float* __restrict__ var1,
    unsigned short* __restrict__ V, unsigned short* __restrict__ U) {
  __shared__ short LA[128 * DPAD];  // A: Tl[m][j]   B: Hl[kk][a]
  __shared__ short LB[128 * DPAD];  // A: Wl[i][j]   B: Rl[i][a] (transposed)
  const int tid = threadIdx.x;
  const int c = tid & 31;    // column quad (4 floats)
  const int rr = tid >> 5;   // row within 8-row step
  const int wv_ = tid >> 6;
  const int lane = tid & 63;
  const int l16 = lane & 15;
  const int quad = lane >> 4;

  f32x4 acc[2][8];
  for (int mt = 0; mt < 2; ++mt)
    for (int nt = 0; nt < 8; ++nt) acc[mt][nt] = (f32x4){0.f, 0.f, 0.f, 0.f};

  if (blockIdx.x < 256) {
    // ---------------- stage A ----------------
    const int k = blockIdx.x >> 1;           // [0,128)
    const int half = blockIdx.x & 1;
    const int rowbase = k * 256 + half * 128;

    f32x4 g  = *(const f32x4*)(gamma1 + c * 4);
    f32x4 be = *(const f32x4*)(beta1  + c * 4);
    f32x4 mu = *(const f32x4*)(mean1  + c * 4);
    f32x4 va = *(const f32x4*)(var1   + c * 4);
    f32x4 sc, bi;
    for (int q = 0; q < 4; ++q) {
      sc[q] = g[q] * rsqrtf(va[q] + BN_EPS);
      bi[q] = be[q] - mu[q] * sc[q];
    }
    const float* tbase = t + (size_t)rowbase * 128;
    const float* wbase = W + (size_t)k * 16384;
    for (int it = 0; it < 16; ++it) {
      const int m = it * 8 + rr;
      f32x4 tv = *(const f32x4*)(tbase + m * 128 + c * 4);
      s16x4 tb;
      for (int q = 0; q < 4; ++q) tb[q] = (short)f2bf(tv[q] * sc[q] + bi[q]);
      *(s16x4*)(&LA[m * DPAD + c * 4]) = tb;
      f32x4 wvv = *(const f32x4*)(wbase + m * 128 + c * 4);
      s16x4 wb;
      for (int q = 0; q < 4; ++q) wb[q] = (short)f2bf(wvv[q]);
      *(s16x4*)(&LB[m * DPAD + c * 4]) = wb;
    }
    __syncthreads();

    // swapped operands: acc = mfma(Wfrag, Tfrag) -> D[i-part, n'-col]
    for (int ks = 0; ks < 4; ++ks) {
      const int K0 = ks * 32 + quad * 8;
      bf16x8 a[2], b[8];
      for (int mt = 0; mt < 2; ++mt)
        a[mt] = *(const bf16x8*)(&LA[(wv_ * 32 + mt * 16 + l16) * DPAD + K0]);
      for (int nt = 0; nt < 8; ++nt)
        b[nt] = *(const bf16x8*)(&LB[(nt * 16 + l16) * DPAD + K0]);
      for (int mt = 0; mt < 2; ++mt)
        for (int nt = 0; nt < 8; ++nt)
          acc[mt][nt] = __builtin_amdgcn_mfma_f32_16x16x32_bf16(b[nt], a[mt], acc[mt][nt], 0, 0, 0);
    }

    // lane holds i = nt*16 + quad*4 + {0..3} of row n' = rowbase + wv*32 + mt*16 + l16
    for (int mt = 0; mt < 2; ++mt) {
      const size_t np = (size_t)(rowbase + wv_ * 32 + mt * 16 + l16) * 128;
      for (int nt = 0; nt < 8; ++nt) {
        unsigned two[2];
        two[0] = pack2bf(acc[mt][nt][0], acc[mt][nt][1]);
        two[1] = pack2bf(acc[mt][nt][2], acc[mt][nt][3]);
        *(uint2*)(V + np + nt * 16 + quad * 4) = *(uint2*)two;
      }
    }
  } else {
    // ---------------- stage B ----------------
    const int low = blockIdx.x - 256;        // [0,256)

    f32x4 g  = *(const f32x4*)(gamma0 + c * 4);
    f32x4 be = *(const f32x4*)(beta0  + c * 4);
    f32x4 mu = *(const f32x4*)(mean0  + c * 4);
    f32x4 va = *(const f32x4*)(var0   + c * 4);
    f32x4 sc, bi;
    for (int q = 0; q < 4; ++q) {
      sc[q] = g[q] * rsqrtf(va[q] + BN_EPS);
      bi[q] = be[q] - mu[q] * sc[q];
    }
    for (int it = 0; it < 16; ++it) {
      const int kk = it * 8 + rr;
      f32x4 hv = *(const f32x4*)(h + ((size_t)(kk * 256 + low)) * 128 + c * 4);
      s16x4 hb;
      for (int q = 0; q < 4; ++q) hb[q] = (short)f2bf(hv[q] * sc[q] + bi[q]);
      *(s16x4*)(&LA[kk * DPAD + c * 4]) = hb;
    }
    // transpose-stage r: thread owns 4x4 block (rows a0..a0+3, cols 4c..4c+3)
    for (int it = 0; it < 4; ++it) {
      const int a0 = it * 32 + rr * 4;
      f32x4 rv[4];
      for (int v = 0; v < 4; ++v)
        rv[v] = *(const f32x4*)(r + ((size_t)(low * 128 + a0 + v)) * 128 + c * 4);
      for (int u = 0; u < 4; ++u) {
        s16x4 w;
        for (int v = 0; v < 4; ++v) w[v] = (short)f2bf(rv[v][u]);
        *(s16x4*)(&LB[(c * 4 + u) * DPAD + a0]) = w;
      }
    }
    __syncthreads();

    // swapped operands: acc = mfma(Rfrag, Hfrag) -> D[i-part, kk-col]
    for (int ks = 0; ks < 4; ++ks) {
      const int K0 = ks * 32 + quad * 8;
      bf16x8 a[2], b[8];
      for (int mt = 0; mt < 2; ++mt)
        a[mt] = *(const bf16x8*)(&LA[(wv_ * 32 + mt * 16 + l16) * DPAD + K0]);
      for (int nt = 0; nt < 8; ++nt)
        b[nt] = *(const bf16x8*)(&LB[(nt * 16 + l16) * DPAD + K0]);
      for (int mt = 0; mt < 2; ++mt)
        for (int nt = 0; nt < 8; ++nt)
          acc[mt][nt] = __builtin_amdgcn_mfma_f32_16x16x32_bf16(b[nt], a[mt], acc[mt][nt], 0, 0, 0);
    }

    // lane holds i = nt*16 + quad*4 + {0..3} of row n' = (wv*32 + mt*16 + l16)*256 + low
    for (int mt = 0; mt < 2; ++mt) {
      const size_t np = ((size_t)(wv_ * 32 + mt * 16 + l16) * 256 + low) * 128;
      for (int nt = 0; nt < 8; ++nt) {
        unsigned two[2];
        two[0] = pack2bf(acc[mt][nt][0], acc[mt][nt][1]);
        two[1] = pack2bf(acc[mt][nt][2], acc[mt][nt][3]);
        *(uint2*)(U + np + nt * 16 + quad * 4) = *(uint2*)two;
      }
    }
  }
}

// ---------------- Stage C: scores[n'] = dot(U[n'], V[n']) ----------------
__global__ __launch_bounds__(256) void k_dot(
    const unsigned short* __restrict__ U, const unsigned short* __restrict__ V,
    float* __restrict__ out) {
  const int tid = threadIdx.x;
  const int row = blockIdx.x * 16 + (tid >> 4);
  const int l = tid & 15;
  const uint4 uv = *(const uint4*)(U + (size_t)row * 128 + l * 8);
  const uint4 vv = *(const uint4*)(V + (size_t)row * 128 + l * 8);
  const unsigned* up = (const unsigned*)&uv;
  const unsigned* vp = (const unsigned*)&vv;
  float s = 0.f;
  for (int q = 0; q < 4; ++q) {
    unsigned a = up[q], b = vp[q];
    s += bf2f((unsigned short)(a & 0xFFFFu)) * bf2f((unsigned short)(b & 0xFFFFu));
    s += bf2f((unsigned short)(a >> 16)) * bf2f((unsigned short)(b >> 16));
  }
  for (int m = 1; m < 16; m <<= 1) s += __shfl_xor(s, m, 16);
  if (l == 0) out[row] = s;
}

extern "C" void kernel_launch(void* const* d_in, const int* in_sizes, int n_in,
                              void* d_out, int out_size, void* d_ws, size_t ws_size,
                              hipStream_t stream) {
  const float* h      = (const float*)d_in[0];
  const float* r      = (const float*)d_in[1];
  const float* t      = (const float*)d_in[2];
  const float* W      = (const float*)d_in[3];
  const float* gamma0 = (const float*)d_in[4];
  const float* beta0  = (const float*)d_in[5];
  const float* mean0  = (const float*)d_in[6];
  const float* var0   = (const float*)d_in[7];
  const float* gamma1 = (const float*)d_in[8];
  const float* beta1  = (const float*)d_in[9];
  const float* mean1  = (const float*)d_in[10];
  const float* var1   = (const float*)d_in[11];
  float* out = (float*)d_out;

  unsigned short* V = (unsigned short*)d_ws;                 // 32768*128 bf16 = 8 MB
  unsigned short* U = V + (size_t)32768 * 128;               // 8 MB more

  k_uv<<<512, 256, 0, stream>>>(h, r, t, W,
                                gamma0, beta0, mean0, var0,
                                gamma1, beta1, mean1, var1, V, U);
  k_dot<<<2048, 256, 0, stream>>>(U, V, out);
}

// Round 4
// 115.059 us; speedup vs baseline: 1.0336x; 1.0154x over previous
//
#include <hip/hip_runtime.h>

// TuckERInteraction: scores[n'] = sum_i u[n',i] * v[n',i]
//   v[n',i] = sum_j W[n'>>8, i, j] * t_bn[n', j]        (stage A, grouped by k = n'>>8)
//   u[n',i] = sum_a h_bn[n',a] * r[(n'&255)*128+a, i]   (stage B, grouped by low = n'&255)
// N = 32768, D = 128. Only V is materialized (bf16, 8 MB in d_ws).
//
// R4: fuse the final dot into stage B's epilogue — u stays in fp32 registers,
// lane loads its matching 4 bf16 of V, FMAs, then shuffle-reduces across the
// 4 quad-lanes sharing a row. Kills U entirely (16.8 MB round trip) and the
// third kernel. Stage A runs first (V producer), stage B+dot second.

typedef __attribute__((ext_vector_type(8))) short bf16x8;   // MFMA A/B fragment (8 bf16)
typedef __attribute__((ext_vector_type(4))) short s16x4;
typedef __attribute__((ext_vector_type(4))) float f32x4;

#define DPAD 136   // LDS row stride (elements)
#define BN_EPS 1e-5f

__device__ inline unsigned short f2bf(float f) {
  unsigned u = __builtin_bit_cast(unsigned, f);
  u += 0x7FFFu + ((u >> 16) & 1u);          // round-to-nearest-even
  return (unsigned short)(u >> 16);
}
__device__ inline float bf2f(unsigned short h) {
  unsigned u = ((unsigned)h) << 16;
  return __builtin_bit_cast(float, u);
}
__device__ inline unsigned pack2bf(float lo, float hi) {
  return (unsigned)f2bf(lo) | ((unsigned)f2bf(hi) << 16);
}

// ---------------- Stage A: V[n', i] = sum_j W[k,i,j] * t_bn[n', j] ----------------
// grid 256: block = (k, half); 128 rows n' = k*256 + half*128 + m
__global__ __launch_bounds__(256) void k_stageA(
    const float* __restrict__ t, const float* __restrict__ W,
    const float* __restrict__ gamma1, const float* __restrict__ beta1,
    const float* __restrict__ mean1, const float* __restrict__ var1,
    unsigned short* __restrict__ V) {
  __shared__ short LA[128 * DPAD];  // Tl[m][j] = bf16(t_bn[rowbase+m, j])
  __shared__ short LB[128 * DPAD];  // Wl[i][j] = bf16(W[k, i, j])
  const int tid = threadIdx.x;
  const int c = tid & 31;
  const int rr = tid >> 5;
  const int wv_ = tid >> 6;
  const int lane = tid & 63;
  const int l16 = lane & 15;
  const int quad = lane >> 4;

  const int k = blockIdx.x >> 1;           // [0,128)
  const int half = blockIdx.x & 1;
  const int rowbase = k * 256 + half * 128;

  f32x4 g  = *(const f32x4*)(gamma1 + c * 4);
  f32x4 be = *(const f32x4*)(beta1  + c * 4);
  f32x4 mu = *(const f32x4*)(mean1  + c * 4);
  f32x4 va = *(const f32x4*)(var1   + c * 4);
  f32x4 sc, bi;
  for (int q = 0; q < 4; ++q) {
    sc[q] = g[q] * rsqrtf(va[q] + BN_EPS);
    bi[q] = be[q] - mu[q] * sc[q];
  }
  const float* tbase = t + (size_t)rowbase * 128;
  const float* wbase = W + (size_t)k * 16384;
  for (int it = 0; it < 16; ++it) {
    const int m = it * 8 + rr;
    f32x4 tv = *(const f32x4*)(tbase + m * 128 + c * 4);
    s16x4 tb;
    for (int q = 0; q < 4; ++q) tb[q] = (short)f2bf(tv[q] * sc[q] + bi[q]);
    *(s16x4*)(&LA[m * DPAD + c * 4]) = tb;
    f32x4 wvv = *(const f32x4*)(wbase + m * 128 + c * 4);
    s16x4 wb;
    for (int q = 0; q < 4; ++q) wb[q] = (short)f2bf(wvv[q]);
    *(s16x4*)(&LB[m * DPAD + c * 4]) = wb;
  }
  __syncthreads();

  f32x4 acc[2][8];
  for (int mt = 0; mt < 2; ++mt)
    for (int nt = 0; nt < 8; ++nt) acc[mt][nt] = (f32x4){0.f, 0.f, 0.f, 0.f};

  // swapped operands: acc = mfma(Wfrag, Tfrag) -> D[i-part(row), n'-part(col)]
  for (int ks = 0; ks < 4; ++ks) {
    const int K0 = ks * 32 + quad * 8;
    bf16x8 a[2], b[8];
    for (int mt = 0; mt < 2; ++mt)
      a[mt] = *(const bf16x8*)(&LA[(wv_ * 32 + mt * 16 + l16) * DPAD + K0]);
    for (int nt = 0; nt < 8; ++nt)
      b[nt] = *(const bf16x8*)(&LB[(nt * 16 + l16) * DPAD + K0]);
    for (int mt = 0; mt < 2; ++mt)
      for (int nt = 0; nt < 8; ++nt)
        acc[mt][nt] = __builtin_amdgcn_mfma_f32_16x16x32_bf16(b[nt], a[mt], acc[mt][nt], 0, 0, 0);
  }

  // lane holds i = nt*16 + quad*4 + {0..3} of row n' = rowbase + wv*32 + mt*16 + l16
  for (int mt = 0; mt < 2; ++mt) {
    const size_t np = (size_t)(rowbase + wv_ * 32 + mt * 16 + l16) * 128;
    for (int nt = 0; nt < 8; ++nt) {
      unsigned two[2];
      two[0] = pack2bf(acc[mt][nt][0], acc[mt][nt][1]);
      two[1] = pack2bf(acc[mt][nt][2], acc[mt][nt][3]);
      *(uint2*)(V + np + nt * 16 + quad * 4) = *(uint2*)two;
    }
  }
}

// ------- Stage B + dot: out[n'] = sum_i (sum_a h_bn[n',a] r[low*128+a, i]) * V[n',i] -------
// grid 256: block = low; rows n' = kk*256 + low, kk in [0,128)
__global__ __launch_bounds__(256) void k_bdot(
    const float* __restrict__ h, const float* __restrict__ r,
    const float* __restrict__ gamma0, const float* __restrict__ beta0,
    const float* __restrict__ mean0, const float* __restrict__ var0,
    const unsigned short* __restrict__ V, float* __restrict__ out) {
  __shared__ short LA[128 * DPAD];  // Hl[kk][a] = bf16(h_bn[kk*256+low, a])
  __shared__ short LB[128 * DPAD];  // Rl[i][a]  = bf16(r[low*128+a, i])   (transposed)
  const int tid = threadIdx.x;
  const int c = tid & 31;
  const int rr = tid >> 5;
  const int wv_ = tid >> 6;
  const int lane = tid & 63;
  const int l16 = lane & 15;
  const int quad = lane >> 4;

  const int low = blockIdx.x;              // [0,256)

  f32x4 g  = *(const f32x4*)(gamma0 + c * 4);
  f32x4 be = *(const f32x4*)(beta0  + c * 4);
  f32x4 mu = *(const f32x4*)(mean0  + c * 4);
  f32x4 va = *(const f32x4*)(var0   + c * 4);
  f32x4 sc, bi;
  for (int q = 0; q < 4; ++q) {
    sc[q] = g[q] * rsqrtf(va[q] + BN_EPS);
    bi[q] = be[q] - mu[q] * sc[q];
  }
  for (int it = 0; it < 16; ++it) {
    const int kk = it * 8 + rr;
    f32x4 hv = *(const f32x4*)(h + ((size_t)(kk * 256 + low)) * 128 + c * 4);
    s16x4 hb;
    for (int q = 0; q < 4; ++q) hb[q] = (short)f2bf(hv[q] * sc[q] + bi[q]);
    *(s16x4*)(&LA[kk * DPAD + c * 4]) = hb;
  }
  // transpose-stage r: thread owns 4x4 block (rows a0..a0+3, cols 4c..4c+3)
  for (int it = 0; it < 4; ++it) {
    const int a0 = it * 32 + rr * 4;
    f32x4 rv[4];
    for (int v = 0; v < 4; ++v)
      rv[v] = *(const f32x4*)(r + ((size_t)(low * 128 + a0 + v)) * 128 + c * 4);
    for (int u = 0; u < 4; ++u) {
      s16x4 w;
      for (int v = 0; v < 4; ++v) w[v] = (short)f2bf(rv[v][u]);
      *(s16x4*)(&LB[(c * 4 + u) * DPAD + a0]) = w;
    }
  }
  __syncthreads();

  f32x4 acc[2][8];
  for (int mt = 0; mt < 2; ++mt)
    for (int nt = 0; nt < 8; ++nt) acc[mt][nt] = (f32x4){0.f, 0.f, 0.f, 0.f};

  // swapped operands: acc = mfma(Rfrag, Hfrag) -> D[i-part(row), kk-part(col)]
  for (int ks = 0; ks < 4; ++ks) {
    const int K0 = ks * 32 + quad * 8;
    bf16x8 a[2], b[8];
    for (int mt = 0; mt < 2; ++mt)
      a[mt] = *(const bf16x8*)(&LA[(wv_ * 32 + mt * 16 + l16) * DPAD + K0]);
    for (int nt = 0; nt < 8; ++nt)
      b[nt] = *(const bf16x8*)(&LB[(nt * 16 + l16) * DPAD + K0]);
    for (int mt = 0; mt < 2; ++mt)
      for (int nt = 0; nt < 8; ++nt)
        acc[mt][nt] = __builtin_amdgcn_mfma_f32_16x16x32_bf16(b[nt], a[mt], acc[mt][nt], 0, 0, 0);
  }

  // fused dot: lane holds u[n', i=nt*16+quad*4+rg] fp32 for row n' = kk*256+low,
  // kk = wv*32 + mt*16 + l16. Load matching V bf16, FMA, reduce across quads.
  for (int mt = 0; mt < 2; ++mt) {
    const int kk = wv_ * 32 + mt * 16 + l16;
    const size_t np = ((size_t)kk * 256 + low) * 128;
    float s = 0.f;
    for (int nt = 0; nt < 8; ++nt) {
      const uint2 vv = *(const uint2*)(V + np + nt * 16 + quad * 4);
      s += acc[mt][nt][0] * bf2f((unsigned short)(vv.x & 0xFFFFu));
      s += acc[mt][nt][1] * bf2f((unsigned short)(vv.x >> 16));
      s += acc[mt][nt][2] * bf2f((unsigned short)(vv.y & 0xFFFFu));
      s += acc[mt][nt][3] * bf2f((unsigned short)(vv.y >> 16));
    }
    s += __shfl_xor(s, 16, 64);
    s += __shfl_xor(s, 32, 64);
    if (quad == 0) out[(size_t)kk * 256 + low] = s;
  }
}

extern "C" void kernel_launch(void* const* d_in, const int* in_sizes, int n_in,
                              void* d_out, int out_size, void* d_ws, size_t ws_size,
                              hipStream_t stream) {
  const float* h      = (const float*)d_in[0];
  const float* r      = (const float*)d_in[1];
  const float* t      = (const float*)d_in[2];
  const float* W      = (const float*)d_in[3];
  const float* gamma0 = (const float*)d_in[4];
  const float* beta0  = (const float*)d_in[5];
  const float* mean0  = (const float*)d_in[6];
  const float* var0   = (const float*)d_in[7];
  const float* gamma1 = (const float*)d_in[8];
  const float* beta1  = (const float*)d_in[9];
  const float* mean1  = (const float*)d_in[10];
  const float* var1   = (const float*)d_in[11];
  float* out = (float*)d_out;

  unsigned short* V = (unsigned short*)d_ws;   // 32768*128 bf16 = 8 MB

  k_stageA<<<256, 256, 0, stream>>>(t, W, gamma1, beta1, mean1, var1, V);
  k_bdot<<<256, 256, 0, stream>>>(h, r, gamma0, beta0, mean0, var0, V, out);
}